// Round 11
// baseline (432.991 us; speedup 1.0000x reference)
//
#include <hip/hip_runtime.h>
#include <stdint.h>

// int8-quantized GEMM: out[m,n] = (sum_k x[m,k]*w[n,k]) * x_scale * w_scale, fp32.
// M=64, K=4096, N=14336. Inputs materialized as int32 -> weights 235 MB.
//
// R5-R10: five structurally different K-loops (full-drain / pipelined ring /
// split-consume / 2x occupancy / DMA-free VGPR->LDS) ALL tie at gemm ~100 us
// (~2.4 TB/s). All theories falsified blind -- gemm never appeared in top-5
// rocprof rows (fills at ~140 us mask it).
// R11 = INSTRUMENTATION ROUND: R9's validated kernel with the K-phase run
// TWICE (acc re-zeroed each rep; rep-1 result is the output -> same answer,
// same work every call). Pushes gemm to ~140-200 us -> visible in top-5 WITH
// counters. Physics probe: rep 1 re-reads the same 235 MB (fits 256 MB L3):
// rep1 ~= rep0 -> CU-side binder; rep1 fast -> HBM/DRAM-path binder.
#define KDIM 4096
#define NDIM 14336
#define KSTEP 256                 // int32 per row per step (1 KB DMA per row)
#define NSTEPS (KDIM / KSTEP)     // 16
#define ROWB 1040                 // LDS row pitch bytes
#define TILEB (16 * ROWB)         // buffer = 16.25 KB; 3 bufs = 48.75 KB
#define MT_BYTES 65536            // xf bytes per m-tile (64 chunks * 1 KB)
#define NREP 2                    // instrumentation: run K-phase twice

typedef int v4i __attribute__((ext_vector_type(4)));

__device__ __forceinline__ int pack4(int w0, int w1, int w2, int w3) {
    int t01 = __builtin_amdgcn_perm(w1, w0, 0x00000400u);
    int t23 = __builtin_amdgcn_perm(w3, w2, 0x00000400u);
    return  __builtin_amdgcn_perm(t23, t01, 0x05040100u);
}

// Pack x [64,4096] int32 -> int8 in MFMA-fragment order (validated R8/R9):
// xf[mtile][chunk c][lane l][16B] = x[mtile*16+(l&15)][c*64+(l>>4)*16 ..+16].
__global__ void pack_x_frag_kernel(const int* __restrict__ xi, int8_t* __restrict__ xf) {
    const int o   = blockIdx.x * 256 + threadIdx.x;  // 0..16383
    const int mt  = o >> 12;
    const int rem = o & 4095;
    const int c   = rem >> 6;
    const int l   = rem & 63;
    const int r   = l & 15;
    const int kg  = l >> 4;
    const int* src = xi + ((size_t)(mt * 16 + r) * KDIM + c * 64 + kg * 16);
    v4i d;
    #pragma unroll
    for (int e = 0; e < 4; ++e) {
        v4i v = *(const v4i*)(src + e * 4);
        d[e] = pack4(v[0], v[1], v[2], v[3]);
    }
    *(v4i*)(xf + (size_t)o * 16) = d;
}

#define GLD_LDS(gptr, lptr) \
    __builtin_amdgcn_global_load_lds( \
        (const __attribute__((address_space(1))) int*)(const void*)(gptr), \
        (__attribute__((address_space(3))) int*)(void*)(lptr), 16, 0, 0)

// R9 kernel verbatim, K-phase wrapped in a rep loop. Block = 8 waves (512 thr),
// one 16-wide N tile. Wave w stages rows 2w,2w+1; consumes chunk c=w&3 for
// m-tiles 2g,2g+1 (g=w>>2). 3-deep ring, vmcnt(2) + raw s_barrier (validated
// R7-R9). Fragment spec (HW-validated R2..R9): row/col=lane&15, k=(lane>>4)*16+j.
__global__ __launch_bounds__(512, 6) void gemm_i8_kernel(
    const int8_t* __restrict__ xf,
    const float*  __restrict__ xs,
    const int*    __restrict__ wq32,
    const float*  __restrict__ wscale,
    float*        __restrict__ out)
{
    __shared__ int8_t lds[3 * TILEB];

    const int tid  = threadIdx.x;
    const int wave = tid >> 6;     // 0..7
    const int lane = tid & 63;
    const int r    = lane & 15;
    const int kg   = lane >> 4;
    const int g    = wave >> 2;    // m-group: m-tiles 2g, 2g+1
    const int c    = wave & 3;     // K-chunk within step
    const int n0   = blockIdx.x * 16;

    const int* wsrc[2];
    int8_t* ldst[2];
    #pragma unroll
    for (int j = 0; j < 2; ++j) {
        wsrc[j] = wq32 + (size_t)(n0 + 2 * wave + j) * KDIM + lane * 4;
        ldst[j] = lds + (2 * wave + j) * ROWB;
    }

    const int8_t* ap = xf + lane * 16;

    v4i acc[2];

    for (int rep = 0; rep < NREP; ++rep) {
        // All waves done with previous rep's LDS reads before re-staging buf 0.
        __syncthreads();

        acc[0] = (v4i){0, 0, 0, 0};
        acc[1] = (v4i){0, 0, 0, 0};

        // ---- Prologue: DMA(0)[2], x(0)[2], DMA(1)[2] ----
        #pragma unroll
        for (int j = 0; j < 2; ++j)
            GLD_LDS(wsrc[j], ldst[j] + 0 * TILEB);

        v4i ax[2];
        #pragma unroll
        for (int t = 0; t < 2; ++t)
            ax[t] = *(const v4i*)(ap + (size_t)(2 * g + t) * MT_BYTES + (size_t)c * 1024);

        #pragma unroll
        for (int j = 0; j < 2; ++j)
            GLD_LDS(wsrc[j] + KSTEP, ldst[j] + 1 * TILEB);

        #pragma unroll
        for (int s = 0; s < NSTEPS; ++s) {
            // Drain own DMA(s)+x(s); leave DMA(s+1) [2 entries] in flight.
            if (s < NSTEPS - 1)
                asm volatile("s_waitcnt vmcnt(2)" ::: "memory");
            else
                asm volatile("s_waitcnt vmcnt(0)" ::: "memory");
            // Raw exec barrier (no compiler vmcnt(0) drain) — validated R7-R9.
            asm volatile("s_barrier" ::: "memory");

            // x(s+1) BEFORE DMA(s+2) so next iter's vmcnt(2) covers it.
            v4i axn[2];
            if (s + 1 < NSTEPS) {
                #pragma unroll
                for (int t = 0; t < 2; ++t)
                    axn[t] = *(const v4i*)(ap + (size_t)(2 * g + t) * MT_BYTES
                                              + (size_t)((s + 1) * 4 + c) * 1024);
            }
            if (s + 2 < NSTEPS) {
                #pragma unroll
                for (int j = 0; j < 2; ++j)
                    GLD_LDS(wsrc[j] + (s + 2) * KSTEP, ldst[j] + ((s + 2) % 3) * TILEB);
            }

            // Consume: lane (r,kg) reads 16 int32 of row r, chunk c; pack; 2 MFMA.
            const v4i* p = (const v4i*)(lds + (s % 3) * TILEB + r * ROWB + c * 256 + kg * 64);
            v4i w0 = p[0], w1 = p[1], w2 = p[2], w3 = p[3];
            v4i b;
            b[0] = pack4(w0[0], w0[1], w0[2], w0[3]);
            b[1] = pack4(w1[0], w1[1], w1[2], w1[3]);
            b[2] = pack4(w2[0], w2[1], w2[2], w2[3]);
            b[3] = pack4(w3[0], w3[1], w3[2], w3[3]);

            acc[0] = __builtin_amdgcn_mfma_i32_16x16x64_i8(ax[0], b, acc[0], 0, 0, 0);
            acc[1] = __builtin_amdgcn_mfma_i32_16x16x64_i8(ax[1], b, acc[1], 0, 0, 0);

            if (s + 1 < NSTEPS) {
                ax[0] = axn[0];
                ax[1] = axn[1];
            }
        }
    }

    // Cross-wave reduce (validated R9): m-tile mt partials in waves g*4+cc.
    __syncthreads();
    int (*red)[2][256] = (int (*)[2][256])&lds[0];
    ((v4i*)red[wave][0])[lane] = acc[0];
    ((v4i*)red[wave][1])[lane] = acc[1];
    __syncthreads();

    if (wave < 4) {
        const int mt = wave;            // m-tile index 0..3
        const int gg = mt >> 1;
        const int tl = mt & 1;
        v4i t0 = ((v4i*)red[gg * 4 + 0][tl])[lane];
        v4i t1 = ((v4i*)red[gg * 4 + 1][tl])[lane];
        v4i t2 = ((v4i*)red[gg * 4 + 2][tl])[lane];
        v4i t3 = ((v4i*)red[gg * 4 + 3][tl])[lane];
        v4i tot = t0 + t1 + t2 + t3;

        // C/D layout (HW-validated R2): col = lane&15, row = (lane>>4)*4 + reg.
        const float scale = xs[0] * wscale[0];
        const int n = n0 + r;
        const int mbase = mt * 16 + kg * 4;
        #pragma unroll
        for (int i = 0; i < 4; ++i)
            out[(size_t)(mbase + i) * NDIM + n] = scale * (float)tot[i];
    }
}

extern "C" void kernel_launch(void* const* d_in, const int* in_sizes, int n_in,
                              void* d_out, int out_size, void* d_ws, size_t ws_size,
                              hipStream_t stream) {
    const int*   xq32   = (const int*)d_in[0];
    const float* xs     = (const float*)d_in[1];
    const int*   wq32   = (const int*)d_in[2];
    const float* wscale = (const float*)d_in[3];
    float* out = (float*)d_out;

    int8_t* xf = (int8_t*)d_ws;  // 256 KB fragment-ordered packed x

    pack_x_frag_kernel<<<64, 256, 0, stream>>>(xq32, xf);

    const int nblocks = NDIM / 16;  // 896
    gemm_i8_kernel<<<nblocks, 512, 0, stream>>>(xf, xs, wq32, wscale, out);
}

// Round 12
// 318.819 us; speedup vs baseline: 1.3581x; 1.3581x over previous
//
#include <hip/hip_runtime.h>
#include <stdint.h>

// int8-quantized GEMM: out[m,n] = (sum_k x[m,k]*w[n,k]) * x_scale * w_scale, fp32.
// M=64, K=4096, N=14336. Inputs materialized as int32 -> weights 235 MB/call.
//
// R5-R10: six structures (drain/ring/split-consume/2x-occupancy/DMA-free) all
// tie at gemm ~100 us. R11 (counters, 2-rep probe): MfmaUtil 1.4%, VALU 3.3%,
// conflicts 3% of cycles, hbm 34%, and an L3-resident re-read runs NO faster
// -> pattern/source/occupancy-independent read-service ceiling ~2.6 TB/s.
// Anomaly: WRITE_SIZE 163 MB (output is 3.7 MB) = L2/L3 insertion+eviction of
// the once-read weight stream sitting in the read path.
// R12: R9 kernel verbatim (3x validated), weight DMA marked NON-TEMPORAL
// (aux=2 = CPol NT bit) to bypass cache insertion. x keeps normal caching
// (shared by all 896 blocks).
#define KDIM 4096
#define NDIM 14336
#define KSTEP 256                 // int32 per row per step (1 KB DMA per row)
#define NSTEPS (KDIM / KSTEP)     // 16
#define ROWB 1040                 // LDS row pitch bytes
#define TILEB (16 * ROWB)         // buffer = 16.25 KB; 3 bufs = 48.75 KB
#define MT_BYTES 65536            // xf bytes per m-tile (64 chunks * 1 KB)

typedef int v4i __attribute__((ext_vector_type(4)));

__device__ __forceinline__ int pack4(int w0, int w1, int w2, int w3) {
    int t01 = __builtin_amdgcn_perm(w1, w0, 0x00000400u);
    int t23 = __builtin_amdgcn_perm(w3, w2, 0x00000400u);
    return  __builtin_amdgcn_perm(t23, t01, 0x05040100u);
}

// Pack x [64,4096] int32 -> int8 in MFMA-fragment order (validated R8-R11):
// xf[mtile][chunk c][lane l][16B] = x[mtile*16+(l&15)][c*64+(l>>4)*16 ..+16].
__global__ void pack_x_frag_kernel(const int* __restrict__ xi, int8_t* __restrict__ xf) {
    const int o   = blockIdx.x * 256 + threadIdx.x;  // 0..16383
    const int mt  = o >> 12;
    const int rem = o & 4095;
    const int c   = rem >> 6;
    const int l   = rem & 63;
    const int r   = l & 15;
    const int kg  = l >> 4;
    const int* src = xi + ((size_t)(mt * 16 + r) * KDIM + c * 64 + kg * 16);
    v4i d;
    #pragma unroll
    for (int e = 0; e < 4; ++e) {
        v4i v = *(const v4i*)(src + e * 4);
        d[e] = pack4(v[0], v[1], v[2], v[3]);
    }
    *(v4i*)(xf + (size_t)o * 16) = d;
}

// Async 16B/lane global->LDS, NON-TEMPORAL (aux=2 = CPol NT): weights are
// read exactly once per call; bypass L2/L3 insertion (R11: 163 MB of clean
// evictions were riding the read path).
#define GLD_LDS_NT(gptr, lptr) \
    __builtin_amdgcn_global_load_lds( \
        (const __attribute__((address_space(1))) int*)(const void*)(gptr), \
        (__attribute__((address_space(3))) int*)(void*)(lptr), 16, 0, 2)

// R9 kernel verbatim. Block = 8 waves (512 thr), one 16-wide N tile. Wave w
// stages rows 2w,2w+1; consumes chunk c=w&3 for m-tiles 2g,2g+1 (g=w>>2).
// 3-deep ring, vmcnt(2) + raw s_barrier (validated R7-R11).
// Fragment spec (HW-validated R2..R11): row/col = lane&15, k = (lane>>4)*16+j.
__global__ __launch_bounds__(512, 6) void gemm_i8_kernel(
    const int8_t* __restrict__ xf,
    const float*  __restrict__ xs,
    const int*    __restrict__ wq32,
    const float*  __restrict__ wscale,
    float*        __restrict__ out)
{
    __shared__ int8_t lds[3 * TILEB];

    const int tid  = threadIdx.x;
    const int wave = tid >> 6;     // 0..7
    const int lane = tid & 63;
    const int r    = lane & 15;
    const int kg   = lane >> 4;
    const int g    = wave >> 2;    // m-group: m-tiles 2g, 2g+1
    const int c    = wave & 3;     // K-chunk within step
    const int n0   = blockIdx.x * 16;

    const int* wsrc[2];
    int8_t* ldst[2];
    #pragma unroll
    for (int j = 0; j < 2; ++j) {
        wsrc[j] = wq32 + (size_t)(n0 + 2 * wave + j) * KDIM + lane * 4;
        ldst[j] = lds + (2 * wave + j) * ROWB;
    }

    const int8_t* ap = xf + lane * 16;

    // ---- Prologue: DMA(0)[2], x(0)[2], DMA(1)[2] ----
    #pragma unroll
    for (int j = 0; j < 2; ++j)
        GLD_LDS_NT(wsrc[j], ldst[j] + 0 * TILEB);

    v4i ax[2];
    #pragma unroll
    for (int t = 0; t < 2; ++t)
        ax[t] = *(const v4i*)(ap + (size_t)(2 * g + t) * MT_BYTES + (size_t)c * 1024);

    #pragma unroll
    for (int j = 0; j < 2; ++j)
        GLD_LDS_NT(wsrc[j] + KSTEP, ldst[j] + 1 * TILEB);

    v4i acc[2];
    acc[0] = (v4i){0, 0, 0, 0};
    acc[1] = (v4i){0, 0, 0, 0};

    #pragma unroll
    for (int s = 0; s < NSTEPS; ++s) {
        // Drain own DMA(s)+x(s); leave DMA(s+1) [2 entries] in flight.
        if (s < NSTEPS - 1)
            asm volatile("s_waitcnt vmcnt(2)" ::: "memory");
        else
            asm volatile("s_waitcnt vmcnt(0)" ::: "memory");
        // Raw exec barrier (no compiler vmcnt(0) drain) — validated R7-R11.
        asm volatile("s_barrier" ::: "memory");

        // x(s+1) BEFORE DMA(s+2) so next iter's vmcnt(2) covers it.
        v4i axn[2];
        if (s + 1 < NSTEPS) {
            #pragma unroll
            for (int t = 0; t < 2; ++t)
                axn[t] = *(const v4i*)(ap + (size_t)(2 * g + t) * MT_BYTES
                                          + (size_t)((s + 1) * 4 + c) * 1024);
        }
        if (s + 2 < NSTEPS) {
            #pragma unroll
            for (int j = 0; j < 2; ++j)
                GLD_LDS_NT(wsrc[j] + (s + 2) * KSTEP, ldst[j] + ((s + 2) % 3) * TILEB);
        }

        // Consume: lane (r,kg) reads 16 int32 of row r, chunk c; pack; 2 MFMA.
        const v4i* p = (const v4i*)(lds + (s % 3) * TILEB + r * ROWB + c * 256 + kg * 64);
        v4i w0 = p[0], w1 = p[1], w2 = p[2], w3 = p[3];
        v4i b;
        b[0] = pack4(w0[0], w0[1], w0[2], w0[3]);
        b[1] = pack4(w1[0], w1[1], w1[2], w1[3]);
        b[2] = pack4(w2[0], w2[1], w2[2], w2[3]);
        b[3] = pack4(w3[0], w3[1], w3[2], w3[3]);

        acc[0] = __builtin_amdgcn_mfma_i32_16x16x64_i8(ax[0], b, acc[0], 0, 0, 0);
        acc[1] = __builtin_amdgcn_mfma_i32_16x16x64_i8(ax[1], b, acc[1], 0, 0, 0);

        if (s + 1 < NSTEPS) {
            ax[0] = axn[0];
            ax[1] = axn[1];
        }
    }

    // Cross-wave reduce (validated R9/R11): m-tile mt partials in waves g*4+cc.
    __syncthreads();
    int (*red)[2][256] = (int (*)[2][256])&lds[0];
    ((v4i*)red[wave][0])[lane] = acc[0];
    ((v4i*)red[wave][1])[lane] = acc[1];
    __syncthreads();

    if (wave < 4) {
        const int mt = wave;            // m-tile index 0..3
        const int gg = mt >> 1;
        const int tl = mt & 1;
        v4i t0 = ((v4i*)red[gg * 4 + 0][tl])[lane];
        v4i t1 = ((v4i*)red[gg * 4 + 1][tl])[lane];
        v4i t2 = ((v4i*)red[gg * 4 + 2][tl])[lane];
        v4i t3 = ((v4i*)red[gg * 4 + 3][tl])[lane];
        v4i tot = t0 + t1 + t2 + t3;

        // C/D layout (HW-validated R2): col = lane&15, row = (lane>>4)*4 + reg.
        const float scale = xs[0] * wscale[0];
        const int n = n0 + r;
        const int mbase = mt * 16 + kg * 4;
        #pragma unroll
        for (int i = 0; i < 4; ++i)
            out[(size_t)(mbase + i) * NDIM + n] = scale * (float)tot[i];
    }
}

extern "C" void kernel_launch(void* const* d_in, const int* in_sizes, int n_in,
                              void* d_out, int out_size, void* d_ws, size_t ws_size,
                              hipStream_t stream) {
    const int*   xq32   = (const int*)d_in[0];
    const float* xs     = (const float*)d_in[1];
    const int*   wq32   = (const int*)d_in[2];
    const float* wscale = (const float*)d_in[3];
    float* out = (float*)d_out;

    int8_t* xf = (int8_t*)d_ws;  // 256 KB fragment-ordered packed x

    pack_x_frag_kernel<<<64, 256, 0, stream>>>(xq32, xf);

    const int nblocks = NDIM / 16;  // 896
    gemm_i8_kernel<<<nblocks, 512, 0, stream>>>(xf, xs, wq32, wscale, out);
}